// Round 8
// baseline (2919.672 us; speedup 1.0000x reference)
//
#include <hip/hip_runtime.h>
#include <hip/hip_bf16.h>
#include <stdint.h>

#define HID 1024
#define G4H 4096
#define BATCH 4096
#define TSTEPS 28
#define DIN 28
#define KTOT 1056   // 1024 (h) + 28 (x_t) + 4 zero pad = 33 * 32
#define NKEY 8
#define NTILES 33

typedef __attribute__((ext_vector_type(8))) __bf16 b16x8;
typedef __attribute__((ext_vector_type(4))) __bf16 b16x4;
typedef __attribute__((ext_vector_type(4))) float f32x4;
typedef __attribute__((address_space(1))) unsigned int u32_g;
typedef __attribute__((address_space(3))) unsigned int u32_l;

__device__ __forceinline__ void async16(const __hip_bfloat16* g, __hip_bfloat16* l) {
  __builtin_amdgcn_global_load_lds((u32_g*)g, (u32_l*)l, 16, 0, 0);
}

__device__ __forceinline__ float sigmoidf_(float x) { return 1.f / (1.f + __expf(-x)); }
__device__ __forceinline__ float tanhfast_(float x) { return 2.f / (1.f + __expf(-2.f * x)) - 1.f; }

__device__ __forceinline__ int nprime(int gate, int j) {
  return ((j >> 4) << 6) + (gate << 4) + (j & 15);
}

// ---- one-time: Wt[n'][k] bf16 (n' = gate-interleaved) ; zero hk0+ck ----
__global__ __launch_bounds__(256) void prep_weights(
    const float* __restrict__ W_hh, const float* __restrict__ W_ih,
    __hip_bfloat16* __restrict__ Wt, float* __restrict__ kstate) {
  __shared__ float tile[64][65];
  const int k0 = blockIdx.x * 64, n0 = blockIdx.y * 64;
  const int tid = threadIdx.x;
  const int fid = (blockIdx.y * gridDim.x + blockIdx.x) * 256 + tid;
  if (fid < 2 * NKEY * HID) kstate[fid] = 0.f;
  for (int i = tid; i < 4096; i += 256) {
    int kk = i >> 6, nn = i & 63;
    int k = k0 + kk;
    float v = 0.f;
    if (k < HID) v = W_hh[k * G4H + n0 + nn];
    else if (k < HID + DIN) v = W_ih[(k - HID) * G4H + n0 + nn];
    tile[kk][nn] = v;
  }
  __syncthreads();
  for (int i = tid; i < 4096; i += 256) {
    int nn = i >> 6, kk = i & 63;
    int k = k0 + kk;
    int n = n0 + nn;
    int np = nprime(n >> 10, n & 1023);
    if (k < KTOT) Wt[(size_t)np * KTOT + k] = __float2bfloat16(tile[kk][nn]);
  }
}

// ---- key pass: one fused step (bf16 weights, fp32 math) ----
__global__ __launch_bounds__(256) void key_step(
    const __hip_bfloat16* __restrict__ Wt, const float* __restrict__ key_seq,
    const float* __restrict__ bias, const float* __restrict__ hk_in,
    float* __restrict__ hk_out, float* __restrict__ ck, int t) {
  __shared__ float sh[NKEY][KTOT];
  __shared__ float sred[32][8][8];
  const int tid = threadIdx.x;
#pragma unroll
  for (int key = 0; key < NKEY; ++key)
    for (int k = tid; k < HID; k += 256) sh[key][k] = hk_in[key * HID + k];
  for (int i = tid; i < NKEY * 32; i += 256) {
    int key = i >> 5, d = i & 31;
    sh[key][HID + d] = (d < DIN) ? key_seq[key * (TSTEPS * DIN) + t * DIN + d] : 0.f;
  }
  __syncthreads();
  const int rowIdx = tid >> 3;
  const int kpart = tid & 7;
  const int gate = rowIdx >> 3, jj = rowIdx & 7;
  const int j0 = blockIdx.x * 8;
  const int np = nprime(gate, j0 + jj);
  const __hip_bfloat16* wrow = Wt + (size_t)np * KTOT + kpart * 132;
  const int kb = kpart * 132;
  float acc[NKEY];
#pragma unroll
  for (int key = 0; key < NKEY; ++key) acc[key] = 0.f;
  for (int kk = 0; kk < 132; kk += 4) {
    b16x4 wv = *(const b16x4*)(wrow + kk);
    float w0 = (float)wv[0], w1 = (float)wv[1], w2 = (float)wv[2], w3 = (float)wv[3];
#pragma unroll
    for (int key = 0; key < NKEY; ++key) {
      const float* s = &sh[key][kb + kk];
      acc[key] += w0 * s[0] + w1 * s[1] + w2 * s[2] + w3 * s[3];
    }
  }
#pragma unroll
  for (int key = 0; key < NKEY; ++key) sred[rowIdx][kpart][key] = acc[key];
  __syncthreads();
  if (tid < 64) {
    int key = tid >> 3, j2 = tid & 7;
    float g[4];
#pragma unroll
    for (int gg = 0; gg < 4; ++gg) {
      float s = 0.f;
#pragma unroll
      for (int p = 0; p < 8; ++p) s += sred[gg * 8 + j2][p][key];
      g[gg] = s + bias[gg * HID + j0 + j2];
    }
    size_t ci = (size_t)key * HID + j0 + j2;
    float cv = sigmoidf_(g[1]) * ck[ci] + sigmoidf_(g[0]) * tanhfast_(g[2]);
    ck[ci] = cv;
    hk_out[ci] = sigmoidf_(g[3]) * tanhfast_(cv);
  }
}

__global__ __launch_bounds__(256) void key_mean(
    const float* __restrict__ hk, const float* __restrict__ ck,
    float* __restrict__ h0, float* __restrict__ c0) {
  int j = blockIdx.x * 256 + threadIdx.x;
  float sh_ = 0.f, sc_ = 0.f;
#pragma unroll
  for (int k = 0; k < NKEY; ++k) { sh_ += hk[k * HID + j]; sc_ += ck[k * HID + j]; }
  h0[j] = sh_ * (1.f / NKEY);
  c0[j] = sc_ * (1.f / NKEY);
}

// ---- main pass init: A panels ----
__global__ __launch_bounds__(256) void main_init(
    const float* __restrict__ h0, const float* __restrict__ x,
    __hip_bfloat16* __restrict__ A0, __hip_bfloat16* __restrict__ A1) {
  int idx = blockIdx.x * 256 + threadIdx.x;  // 4096*1056
  int b = idx / KTOT, col = idx - b * KTOT;
  if (col < HID) {
    A0[idx] = __float2bfloat16(h0[col]);
  } else if (col < HID + DIN) {
    A0[idx] = __float2bfloat16(x[b * (TSTEPS * DIN) + (col - HID)]);
  } else {
    A0[idx] = __float2bfloat16(0.f);
    A1[idx] = __float2bfloat16(0.f);
  }
}

// ---- c init (transposed layout cT[j][b]) ----
__global__ __launch_bounds__(256) void c_init(
    const float* __restrict__ c0, float* __restrict__ cT) {
  int i4 = blockIdx.x * 256 + threadIdx.x;   // HID*BATCH/4
  float v = c0[i4 >> 10];
  float4 w = {v, v, v, v};
  ((float4*)cT)[i4] = w;
}

// ---- fused GEMM + LSTM cell: 256x128 tile, 3-buf depth-2 counted-vmcnt ----
// Grid dim3(32 jt, 16 mt) = 512 blocks = 2/CU. 512 thr = 8 waves (4M x 2N).
__global__ __launch_bounds__(512, 4) void gemm_lstm(
    const __hip_bfloat16* __restrict__ Ain, const __hip_bfloat16* __restrict__ Wt,
    const float* __restrict__ bias, float* __restrict__ cst,
    __hip_bfloat16* __restrict__ Aout, const float* __restrict__ x,
    float* __restrict__ hfin, int t) {
  __shared__ alignas(16) __hip_bfloat16 sA[3][256 * 32];      // 48 KB
  __shared__ alignas(16) __hip_bfloat16 sB[3][4 * 32 * 32];   // 24 KB
  const int tid = threadIdx.x;
  const int lane = tid & 63, wave = tid >> 6;
  const int wr = wave >> 1, wc = wave & 1;    // wr 0..3, wc 0..1
  const int jt = blockIdx.x, mt = blockIdx.y;
  const int brow = mt * 256, j0 = jt * 32;
  const int lrow = lane & 15, kq = lane >> 4;
  const int sx = (lrow >> 1) & 3;

  // staging: LDS dest linear; source k-slot XOR-swizzled (proven 0-conflict)
  const int kqs = (tid & 3) ^ ((tid >> 3) & 3);
  const int sArow = tid >> 2;                 // 0..127 (+128 for 2nd granule)
  const int sBr = tid >> 2;                   // B row 0..127 = gate*32 + jl
  const __hip_bfloat16* gA0 = Ain + (size_t)(brow + sArow) * KTOT + kqs * 8;
  const __hip_bfloat16* gA1 = gA0 + (size_t)128 * KTOT;
  const __hip_bfloat16* gB = Wt + (size_t)nprime(sBr >> 5, j0 + (sBr & 31)) * KTOT + kqs * 8;

  // fragment-read granule indices (16B units)
  int iA[4];
#pragma unroll
  for (int m = 0; m < 4; ++m) {
    int row = wr * 64 + m * 16 + lrow;
    iA[m] = row * 4 + (kq ^ sx);
  }
  int iB[4];
  {
    int jl = wc * 16 + lrow;
#pragma unroll
    for (int g = 0; g < 4; ++g) iB[g] = (g * 32 + jl) * 4 + (kq ^ sx);
  }

  // prefetch c (transposed) + bias into registers; latency hides under K-loop
  const int j = j0 + wc * 16 + lrow;
  float* cbase = cst + (size_t)j * BATCH + brow + wr * 64 + kq * 4;
  f32x4 creg[4];
#pragma unroll
  for (int m = 0; m < 4; ++m) creg[m] = *(const f32x4*)(cbase + m * 16);
  const float b_i = bias[j], b_f = bias[HID + j];
  const float b_g = bias[2 * HID + j], b_o = bias[3 * HID + j];

  f32x4 acc[4][4] = {};   // [gate][m]

#define STAGE(buf, kt) do { \
    async16(gA0 + (size_t)(kt) * 32, &sA[buf][tid * 8]); \
    async16(gA1 + (size_t)(kt) * 32, &sA[buf][4096 + tid * 8]); \
    async16(gB + (size_t)(kt) * 32, &sB[buf][tid * 8]); \
  } while (0)

  // prologue: tiles 0,1 staged (6 loads/wave in flight)
  STAGE(0, 0);
  STAGE(1, 1);
  asm volatile("s_waitcnt vmcnt(3)" ::: "memory");   // tile0 landed; tile1 in flight
  __builtin_amdgcn_s_barrier();

#pragma unroll 3
  for (int kt = 0; kt < NTILES; ++kt) {
    const int cb = kt % 3;
    if (kt + 2 < NTILES) STAGE((kt + 2) % 3, kt + 2);
    const b16x8* cA = (const b16x8*)sA[cb];
    const b16x8* cB = (const b16x8*)sB[cb];
    b16x8 af[4], bf[4];
#pragma unroll
    for (int m = 0; m < 4; ++m) af[m] = cA[iA[m]];
#pragma unroll
    for (int g = 0; g < 4; ++g) bf[g] = cB[iB[g]];
    __builtin_amdgcn_s_setprio(1);
#pragma unroll
    for (int g = 0; g < 4; ++g)
#pragma unroll
      for (int m = 0; m < 4; ++m)
        acc[g][m] = __builtin_amdgcn_mfma_f32_16x16x32_bf16(af[m], bf[g], acc[g][m], 0, 0, 0);
    __builtin_amdgcn_s_setprio(0);
    // counted wait (fence-paired with barrier): tile kt+1 must be landed
    if (kt + 2 < NTILES)      asm volatile("s_waitcnt vmcnt(3)" ::: "memory");
    else if (kt + 1 < NTILES) asm volatile("s_waitcnt vmcnt(0)" ::: "memory");
    __builtin_amdgcn_s_barrier();
  }
#undef STAGE

  // ---- fused LSTM cell epilogue; h via LDS transpose ----
  __hip_bfloat16* sH = &sA[0][0];   // 256 x 32 bf16 (16 KB)
#pragma unroll
  for (int m = 0; m < 4; ++m) {
    f32x4 cv4 = creg[m];
#pragma unroll
    for (int r = 0; r < 4; ++r) {
      float gi = acc[0][m][r] + b_i;
      float gf = acc[1][m][r] + b_f;
      float gg = acc[2][m][r] + b_g;
      float go = acc[3][m][r] + b_o;
      float cv = sigmoidf_(gf) * cv4[r] + sigmoidf_(gi) * tanhfast_(gg);
      cv4[r] = cv;
      float h = sigmoidf_(go) * tanhfast_(cv);
      const int lr = wr * 64 + m * 16 + kq * 4 + r;
      sH[lr * 32 + wc * 16 + lrow] = __float2bfloat16(h);
      if (t == TSTEPS - 1) hfin[(size_t)(brow + lr) * HID + j] = h;
    }
    *(f32x4*)(cbase + m * 16) = cv4;
  }
  __syncthreads();
  {
    const b16x8* sHv = (const b16x8*)sH;
    const int lr = tid >> 1, seg = tid & 1;
    __hip_bfloat16* dst = Aout + (size_t)(brow + lr) * KTOT + j0 + seg * 16;
    b16x8 v0 = sHv[lr * 4 + seg * 2];
    b16x8 v1 = sHv[lr * 4 + seg * 2 + 1];
    *(b16x8*)dst = v0;
    *(b16x8*)(dst + 8) = v1;
  }
  // inject next x slice (jt==0 blocks own their 256 rows)
  if (jt == 0 && t + 1 < TSTEPS) {
    for (int i = tid; i < 256 * DIN; i += 512) {
      int rr = i / DIN, d = i - rr * DIN;
      Aout[(size_t)(brow + rr) * KTOT + HID + d] =
          __float2bfloat16(x[(size_t)(brow + rr) * (TSTEPS * DIN) + (t + 1) * DIN + d]);
    }
  }
}

// ---- out = hfin @ W_cls + b_cls ----
__global__ __launch_bounds__(256) void classifier(
    const float* __restrict__ hfin, const float* __restrict__ W_cls,
    const float* __restrict__ b_cls, float* __restrict__ out) {
  __shared__ float sw[HID * 10];
  __shared__ float sred[10][257];
  const int b = blockIdx.x, tid = threadIdx.x;
  for (int i = tid; i < HID * 10; i += 256) sw[i] = W_cls[i];
  __syncthreads();
  float acc[10];
#pragma unroll
  for (int cls = 0; cls < 10; ++cls) acc[cls] = 0.f;
  for (int j = tid; j < HID; j += 256) {
    float hv = hfin[(size_t)b * HID + j];
#pragma unroll
    for (int cls = 0; cls < 10; ++cls) acc[cls] += hv * sw[j * 10 + cls];
  }
#pragma unroll
  for (int cls = 0; cls < 10; ++cls) sred[cls][tid] = acc[cls];
  __syncthreads();
  for (int off = 128; off > 0; off >>= 1) {
    if (tid < off)
#pragma unroll
      for (int cls = 0; cls < 10; ++cls) sred[cls][tid] += sred[cls][tid + off];
    __syncthreads();
  }
  if (tid < 10) out[b * 10 + tid] = sred[tid][0] + b_cls[tid];
}

extern "C" void kernel_launch(void* const* d_in, const int* in_sizes, int n_in,
                              void* d_out, int out_size, void* d_ws, size_t ws_size,
                              hipStream_t stream) {
  const float* x      = (const float*)d_in[0];
  const float* keyseq = (const float*)d_in[1];
  const float* W_ih   = (const float*)d_in[2];
  const float* W_hh   = (const float*)d_in[3];
  const float* bias   = (const float*)d_in[4];
  const float* W_cls  = (const float*)d_in[5];
  const float* b_cls  = (const float*)d_in[6];
  float* out = (float*)d_out;
  (void)in_sizes; (void)n_in; (void)out_size; (void)ws_size;

  char* p = (char*)d_ws;
  auto alloc = [&](size_t bytes) { char* r = p; p += (bytes + 255) & ~(size_t)255; return r; };
  __hip_bfloat16* Wt = (__hip_bfloat16*)alloc((size_t)G4H * KTOT * 2);
  __hip_bfloat16* A0 = (__hip_bfloat16*)alloc((size_t)BATCH * KTOT * 2);
  __hip_bfloat16* A1 = (__hip_bfloat16*)alloc((size_t)BATCH * KTOT * 2);
  float* cT   = (float*)alloc((size_t)BATCH * HID * 4);   // transposed [HID][BATCH]
  float* hfin = (float*)alloc((size_t)BATCH * HID * 4);
  float* hk0  = (float*)alloc((size_t)NKEY * HID * 4);    // hk0 then ck contiguous
  float* ck   = (float*)alloc((size_t)NKEY * HID * 4);
  float* hk1  = (float*)alloc((size_t)NKEY * HID * 4);
  float* h0   = (float*)alloc((size_t)HID * 4);
  float* c0   = (float*)alloc((size_t)HID * 4);

  prep_weights<<<dim3(17, 64), 256, 0, stream>>>(W_hh, W_ih, Wt, hk0);

  float* kbuf[2] = {hk0, hk1};
  for (int t = 0; t < TSTEPS; ++t)
    key_step<<<128, 256, 0, stream>>>(Wt, keyseq, bias, kbuf[t & 1], kbuf[(t + 1) & 1], ck, t);
  key_mean<<<4, 256, 0, stream>>>(hk0, ck, h0, c0);

  main_init<<<(BATCH * KTOT) / 256, 256, 0, stream>>>(h0, x, A0, A1);
  c_init<<<(BATCH * HID / 4) / 256, 256, 0, stream>>>(c0, cT);

  __hip_bfloat16* Ab[2] = {A0, A1};
  for (int t = 0; t < TSTEPS; ++t)
    gemm_lstm<<<dim3(32, 16), 512, 0, stream>>>(Ab[t & 1], Wt, bias, cT,
                                                Ab[(t + 1) & 1], x, hfin, t);
  classifier<<<BATCH, 256, 0, stream>>>(hfin, W_cls, b_cls, out);
}

// Round 9
// 1939.316 us; speedup vs baseline: 1.5055x; 1.5055x over previous
//
#include <hip/hip_runtime.h>
#include <hip/hip_bf16.h>
#include <stdint.h>

#define HID 1024
#define G4H 4096
#define BATCH 4096
#define TSTEPS 28
#define DIN 28
#define KTOT 1056   // 1024 (h) + 28 (x_t) + 4 zero pad = 33 * 32
#define NKEY 8
#define NTILES 33

typedef __attribute__((ext_vector_type(8))) __bf16 b16x8;
typedef __attribute__((ext_vector_type(4))) __bf16 b16x4;
typedef __attribute__((ext_vector_type(4))) float f32x4;
typedef __attribute__((address_space(1))) unsigned int u32_g;
typedef __attribute__((address_space(3))) unsigned int u32_l;

__device__ __forceinline__ void async16(const __hip_bfloat16* g, __hip_bfloat16* l) {
  __builtin_amdgcn_global_load_lds((u32_g*)g, (u32_l*)l, 16, 0, 0);
}

__device__ __forceinline__ float sigmoidf_(float x) { return 1.f / (1.f + __expf(-x)); }
__device__ __forceinline__ float tanhfast_(float x) { return 2.f / (1.f + __expf(-2.f * x)) - 1.f; }

__device__ __forceinline__ int nprime(int gate, int j) {
  return ((j >> 4) << 6) + (gate << 4) + (j & 15);
}

// ---- one-time: Wt[n'][k] bf16 (n' = gate-interleaved) ; zero hk0+ck ----
__global__ __launch_bounds__(256) void prep_weights(
    const float* __restrict__ W_hh, const float* __restrict__ W_ih,
    __hip_bfloat16* __restrict__ Wt, float* __restrict__ kstate) {
  __shared__ float tile[64][65];
  const int k0 = blockIdx.x * 64, n0 = blockIdx.y * 64;
  const int tid = threadIdx.x;
  const int fid = (blockIdx.y * gridDim.x + blockIdx.x) * 256 + tid;
  if (fid < 2 * NKEY * HID) kstate[fid] = 0.f;
  for (int i = tid; i < 4096; i += 256) {
    int kk = i >> 6, nn = i & 63;
    int k = k0 + kk;
    float v = 0.f;
    if (k < HID) v = W_hh[k * G4H + n0 + nn];
    else if (k < HID + DIN) v = W_ih[(k - HID) * G4H + n0 + nn];
    tile[kk][nn] = v;
  }
  __syncthreads();
  for (int i = tid; i < 4096; i += 256) {
    int nn = i >> 6, kk = i & 63;
    int k = k0 + kk;
    int n = n0 + nn;
    int np = nprime(n >> 10, n & 1023);
    if (k < KTOT) Wt[(size_t)np * KTOT + k] = __float2bfloat16(tile[kk][nn]);
  }
}

// ---- key pass: one fused step (bf16 weights, fp32 math) ----
__global__ __launch_bounds__(256) void key_step(
    const __hip_bfloat16* __restrict__ Wt, const float* __restrict__ key_seq,
    const float* __restrict__ bias, const float* __restrict__ hk_in,
    float* __restrict__ hk_out, float* __restrict__ ck, int t) {
  __shared__ float sh[NKEY][KTOT];
  __shared__ float sred[32][8][8];
  const int tid = threadIdx.x;
#pragma unroll
  for (int key = 0; key < NKEY; ++key)
    for (int k = tid; k < HID; k += 256) sh[key][k] = hk_in[key * HID + k];
  for (int i = tid; i < NKEY * 32; i += 256) {
    int key = i >> 5, d = i & 31;
    sh[key][HID + d] = (d < DIN) ? key_seq[key * (TSTEPS * DIN) + t * DIN + d] : 0.f;
  }
  __syncthreads();
  const int rowIdx = tid >> 3;
  const int kpart = tid & 7;
  const int gate = rowIdx >> 3, jj = rowIdx & 7;
  const int j0 = blockIdx.x * 8;
  const int np = nprime(gate, j0 + jj);
  const __hip_bfloat16* wrow = Wt + (size_t)np * KTOT + kpart * 132;
  const int kb = kpart * 132;
  float acc[NKEY];
#pragma unroll
  for (int key = 0; key < NKEY; ++key) acc[key] = 0.f;
  for (int kk = 0; kk < 132; kk += 4) {
    b16x4 wv = *(const b16x4*)(wrow + kk);
    float w0 = (float)wv[0], w1 = (float)wv[1], w2 = (float)wv[2], w3 = (float)wv[3];
#pragma unroll
    for (int key = 0; key < NKEY; ++key) {
      const float* s = &sh[key][kb + kk];
      acc[key] += w0 * s[0] + w1 * s[1] + w2 * s[2] + w3 * s[3];
    }
  }
#pragma unroll
  for (int key = 0; key < NKEY; ++key) sred[rowIdx][kpart][key] = acc[key];
  __syncthreads();
  if (tid < 64) {
    int key = tid >> 3, j2 = tid & 7;
    float g[4];
#pragma unroll
    for (int gg = 0; gg < 4; ++gg) {
      float s = 0.f;
#pragma unroll
      for (int p = 0; p < 8; ++p) s += sred[gg * 8 + j2][p][key];
      g[gg] = s + bias[gg * HID + j0 + j2];
    }
    size_t ci = (size_t)key * HID + j0 + j2;
    float cv = sigmoidf_(g[1]) * ck[ci] + sigmoidf_(g[0]) * tanhfast_(g[2]);
    ck[ci] = cv;
    hk_out[ci] = sigmoidf_(g[3]) * tanhfast_(cv);
  }
}

__global__ __launch_bounds__(256) void key_mean(
    const float* __restrict__ hk, const float* __restrict__ ck,
    float* __restrict__ h0, float* __restrict__ c0) {
  int j = blockIdx.x * 256 + threadIdx.x;
  float sh_ = 0.f, sc_ = 0.f;
#pragma unroll
  for (int k = 0; k < NKEY; ++k) { sh_ += hk[k * HID + j]; sc_ += ck[k * HID + j]; }
  h0[j] = sh_ * (1.f / NKEY);
  c0[j] = sc_ * (1.f / NKEY);
}

// ---- main pass init ----
__global__ __launch_bounds__(256) void main_init(
    const float* __restrict__ h0, const float* __restrict__ c0,
    const float* __restrict__ x, __hip_bfloat16* __restrict__ A0,
    __hip_bfloat16* __restrict__ A1, float* __restrict__ c) {
  int idx = blockIdx.x * 256 + threadIdx.x;  // 4096*1056
  int b = idx / KTOT, col = idx - b * KTOT;
  if (col < HID) {
    A0[idx] = __float2bfloat16(h0[col]);
    c[b * HID + col] = c0[col];
  } else if (col < HID + DIN) {
    A0[idx] = __float2bfloat16(x[b * (TSTEPS * DIN) + (col - HID)]);
  } else {
    A0[idx] = __float2bfloat16(0.f);
    A1[idx] = __float2bfloat16(0.f);
  }
}

// ---- fused GEMM + LSTM cell: 256x128 tile, R7 2-buffer pipeline ----
// 512 blocks = 2/CU. XCD-chunked remap: XCD x (= flat%8, HW round-robin)
// owns an 8-jt x 8-mt chunk -> per-XCD L2 working set 2.16MB Wt + 4.32MB A
// (vs 1.1 + 8.65 unchunked); Wt slice stable across all 28 dispatches.
__global__ __launch_bounds__(512, 4) void gemm_lstm(
    const __hip_bfloat16* __restrict__ Ain, const __hip_bfloat16* __restrict__ Wt,
    const float* __restrict__ bias, float* __restrict__ cst,
    __hip_bfloat16* __restrict__ Aout, const float* __restrict__ x,
    float* __restrict__ hfin, int t) {
  __shared__ alignas(16) __hip_bfloat16 sA[2][256 * 32];      // 2 x 16KB
  __shared__ alignas(16) __hip_bfloat16 sB[2][4 * 32 * 32];   // 2 x 8KB
  const int tid = threadIdx.x;
  const int lane = tid & 63, wave = tid >> 6;
  const int wr = wave >> 1, wc = wave & 1;    // wr 0..3, wc 0..1
  // bijective XCD-chunk remap: flat -> (jt, mt)
  const int flat = blockIdx.y * 32 + blockIdx.x;
  const int xcd = flat & 7, li = flat >> 3;          // li 0..63
  const int jt = (xcd & 3) * 8 + (li & 7);           // 0..31
  const int mt = (xcd >> 2) * 8 + (li >> 3);         // 0..15
  const int brow = mt * 256, j0 = jt * 32;
  const int lrow = lane & 15, kq = lane >> 4;
  const int sx = (lrow >> 1) & 3;

  // staging: LDS dest linear; source k-slot XOR-swizzled (proven 0-conflict)
  const int kqs = (tid & 3) ^ ((tid >> 3) & 3);
  const int sArow = tid >> 2;                 // 0..127 (+128 for second granule)
  const int sBr = tid >> 2;                   // B row 0..127 = gate*32 + jl
  const __hip_bfloat16* gA0 = Ain + (size_t)(brow + sArow) * KTOT + kqs * 8;
  const __hip_bfloat16* gA1 = gA0 + (size_t)128 * KTOT;
  const __hip_bfloat16* gB = Wt + (size_t)nprime(sBr >> 5, j0 + (sBr & 31)) * KTOT + kqs * 8;

  // fragment-read granule indices (16B units), constant across K-steps
  int iA[4];
#pragma unroll
  for (int m = 0; m < 4; ++m) {
    int row = wr * 64 + m * 16 + lrow;
    iA[m] = row * 4 + (kq ^ sx);
  }
  int iB[4];
  {
    int jl = wc * 16 + lrow;
#pragma unroll
    for (int g = 0; g < 4; ++g) iB[g] = (g * 32 + jl) * 4 + (kq ^ sx);
  }

  f32x4 acc[4][4] = {};   // [gate][m]

#define STAGE(buf, kt) do { \
    async16(gA0 + (size_t)(kt) * 32, &sA[buf][tid * 8]); \
    async16(gA1 + (size_t)(kt) * 32, &sA[buf][4096 + tid * 8]); \
    async16(gB + (size_t)(kt) * 32, &sB[buf][tid * 8]); \
  } while (0)

  STAGE(0, 0);
  __syncthreads();

  for (int kt = 0; kt < NTILES; ++kt) {
    if (kt + 1 < NTILES) STAGE((kt + 1) & 1, kt + 1);
    const b16x8* cA = (const b16x8*)sA[kt & 1];
    const b16x8* cB = (const b16x8*)sB[kt & 1];
    b16x8 af[4], bf[4];
#pragma unroll
    for (int m = 0; m < 4; ++m) af[m] = cA[iA[m]];
#pragma unroll
    for (int g = 0; g < 4; ++g) bf[g] = cB[iB[g]];
    __builtin_amdgcn_s_setprio(1);
#pragma unroll
    for (int g = 0; g < 4; ++g)
#pragma unroll
      for (int m = 0; m < 4; ++m)
        acc[g][m] = __builtin_amdgcn_mfma_f32_16x16x32_bf16(af[m], bf[g], acc[g][m], 0, 0, 0);
    __builtin_amdgcn_s_setprio(0);
    __syncthreads();   // drains staged loads (vmcnt) + frag reads (lgkm)
  }
#undef STAGE

  // ---- fused LSTM cell epilogue ----
  const int j = j0 + wc * 16 + lrow;
  const float b_i = bias[j], b_f = bias[HID + j];
  const float b_g = bias[2 * HID + j], b_o = bias[3 * HID + j];
#pragma unroll
  for (int m = 0; m < 4; ++m) {
    const int row0 = brow + wr * 64 + m * 16 + kq * 4;
#pragma unroll
    for (int r = 0; r < 4; ++r) {
      const int row = row0 + r;
      const size_t ci = (size_t)row * HID + j;
      float gi = acc[0][m][r] + b_i;
      float gf = acc[1][m][r] + b_f;
      float gg = acc[2][m][r] + b_g;
      float go = acc[3][m][r] + b_o;
      float cv = sigmoidf_(gf) * cst[ci] + sigmoidf_(gi) * tanhfast_(gg);
      cst[ci] = cv;
      float h = sigmoidf_(go) * tanhfast_(cv);
      Aout[(size_t)row * KTOT + j] = __float2bfloat16(h);
      if (t == TSTEPS - 1) hfin[ci] = h;
    }
  }
  // inject next x slice (jt==0 blocks own their 256 rows)
  if (jt == 0 && t + 1 < TSTEPS) {
    for (int i = tid; i < 256 * DIN; i += 512) {
      int rr = i / DIN, d = i - rr * DIN;
      Aout[(size_t)(brow + rr) * KTOT + HID + d] =
          __float2bfloat16(x[(size_t)(brow + rr) * (TSTEPS * DIN) + (t + 1) * DIN + d]);
    }
  }
}

// ---- out = hfin @ W_cls + b_cls ----
__global__ __launch_bounds__(256) void classifier(
    const float* __restrict__ hfin, const float* __restrict__ W_cls,
    const float* __restrict__ b_cls, float* __restrict__ out) {
  __shared__ float sw[HID * 10];
  __shared__ float sred[10][257];
  const int b = blockIdx.x, tid = threadIdx.x;
  for (int i = tid; i < HID * 10; i += 256) sw[i] = W_cls[i];
  __syncthreads();
  float acc[10];
#pragma unroll
  for (int cls = 0; cls < 10; ++cls) acc[cls] = 0.f;
  for (int j = tid; j < HID; j += 256) {
    float hv = hfin[(size_t)b * HID + j];
#pragma unroll
    for (int cls = 0; cls < 10; ++cls) acc[cls] += hv * sw[j * 10 + cls];
  }
#pragma unroll
  for (int cls = 0; cls < 10; ++cls) sred[cls][tid] = acc[cls];
  __syncthreads();
  for (int off = 128; off > 0; off >>= 1) {
    if (tid < off)
#pragma unroll
      for (int cls = 0; cls < 10; ++cls) sred[cls][tid] += sred[cls][tid + off];
    __syncthreads();
  }
  if (tid < 10) out[b * 10 + tid] = sred[tid][0] + b_cls[tid];
}

extern "C" void kernel_launch(void* const* d_in, const int* in_sizes, int n_in,
                              void* d_out, int out_size, void* d_ws, size_t ws_size,
                              hipStream_t stream) {
  const float* x      = (const float*)d_in[0];
  const float* keyseq = (const float*)d_in[1];
  const float* W_ih   = (const float*)d_in[2];
  const float* W_hh   = (const float*)d_in[3];
  const float* bias   = (const float*)d_in[4];
  const float* W_cls  = (const float*)d_in[5];
  const float* b_cls  = (const float*)d_in[6];
  float* out = (float*)d_out;
  (void)in_sizes; (void)n_in; (void)out_size; (void)ws_size;

  char* p = (char*)d_ws;
  auto alloc = [&](size_t bytes) { char* r = p; p += (bytes + 255) & ~(size_t)255; return r; };
  __hip_bfloat16* Wt = (__hip_bfloat16*)alloc((size_t)G4H * KTOT * 2);
  __hip_bfloat16* A0 = (__hip_bfloat16*)alloc((size_t)BATCH * KTOT * 2);
  __hip_bfloat16* A1 = (__hip_bfloat16*)alloc((size_t)BATCH * KTOT * 2);
  float* c    = (float*)alloc((size_t)BATCH * HID * 4);
  float* hfin = (float*)alloc((size_t)BATCH * HID * 4);
  float* hk0  = (float*)alloc((size_t)NKEY * HID * 4);   // hk0 then ck contiguous
  float* ck   = (float*)alloc((size_t)NKEY * HID * 4);
  float* hk1  = (float*)alloc((size_t)NKEY * HID * 4);
  float* h0   = (float*)alloc((size_t)HID * 4);
  float* c0   = (float*)alloc((size_t)HID * 4);

  prep_weights<<<dim3(17, 64), 256, 0, stream>>>(W_hh, W_ih, Wt, hk0);

  float* kbuf[2] = {hk0, hk1};
  for (int t = 0; t < TSTEPS; ++t)
    key_step<<<128, 256, 0, stream>>>(Wt, keyseq, bias, kbuf[t & 1], kbuf[(t + 1) & 1], ck, t);
  key_mean<<<4, 256, 0, stream>>>(hk0, ck, h0, c0);

  main_init<<<(BATCH * KTOT) / 256, 256, 0, stream>>>(h0, c0, x, A0, A1, c);

  __hip_bfloat16* Ab[2] = {A0, A1};
  for (int t = 0; t < TSTEPS; ++t)
    gemm_lstm<<<dim3(32, 16), 512, 0, stream>>>(Ab[t & 1], Wt, bias, c,
                                                Ab[(t + 1) & 1], x, hfin, t);
  classifier<<<BATCH, 256, 0, stream>>>(hfin, W_cls, b_cls, out);
}